// Round 4
// baseline (14439.561 us; speedup 1.0000x reference)
//
#include <hip/hip_runtime.h>
#include <hip/hip_bf16.h>
#include <hip/hip_cooperative_groups.h>
namespace cg = cooperative_groups;

#define NT 256

struct Pars {
  const float* x;
  const int* L1r; const int* L1c; const float* L1v;
  const int* L2r; const int* L2c; const float* L2v;
  const float* W1; const float* b1;
  const float* W2; const float* b2;
  const float* fW1; const float* fb1;
  const float* fW2; const float* fb2;
  float* out;
  int *cnt1, *rs1, *ccol1, *cnt2, *rs2, *ccol2;
  float *cval1, *cval2, *wT2, *fc1o;
  float *T1, *zA, *zB, *h2T;
};

__device__ void scan_block(int* cnt, int* rs, int V, int nnz, int t, float* smf) {
  int* sums = (int*)smf;
  int chunk = V / NT;
  int base = t * chunk;
  int s = 0;
  for (int i = 0; i < chunk; ++i) s += cnt[base + i];
  sums[t] = s;
  __syncthreads();
  if (t == 0) {
    int run = 0;
    for (int i = 0; i < NT; ++i) { int c = sums[i]; sums[i] = run; run += c; }
  }
  __syncthreads();
  int pfx = sums[t];
  for (int i = 0; i < chunk; ++i) {
    int c = cnt[base + i];
    rs[base + i] = pfx;
    cnt[base + i] = pfx;   // cursor for scatter
    pfx += c;
  }
  if (t == 0) rs[V] = nnz;
}

// Static LDS kept at exactly 16 KB so even a 64 KB/CU occupancy belief
// yields 4 blocks/CU -> cooperative grid of 1024 is accepted.
__global__ void __launch_bounds__(NT, 4) k_all(Pars p) {
  cg::grid_group grid = cg::this_grid();
  __shared__ float sm[4096];            // 16384 B
  const int bid = blockIdx.x, t = threadIdx.x;
  const int G = gridDim.x;

  // ---------- P0: histograms, W2 transpose ([k][fin][f]), fc1o zero ----------
  for (int lt = bid; lt < 520; lt += G) {
    if (lt < 128) {
      int e = lt * NT + t;                      // 32768 L1 edges
      atomicAdd(&p.cnt1[p.L1r[e]], 1);
    } else if (lt < 192) {
      int e = (lt - 128) * NT + t;              // 16384 L2 edges
      atomicAdd(&p.cnt2[p.L2r[e]], 1);
    } else if (lt < 392) {                      // wT2[k*2048 + fin*64 + f]
      int idx = (lt - 192) * NT + t;            // 51200
      int k = idx >> 11, r = idx & 2047;
      int fin = r >> 6, f = r & 63;
      p.wT2[idx] = p.W2[f * 800 + fin * 25 + k];
    } else {
      p.fc1o[(lt - 392) * NT + t] = 0.f;        // 32768
    }
  }
  __threadfence();
  grid.sync();

  // ---------- P1: prefix scans ----------
  if (bid == 0) scan_block(p.cnt1, p.rs1, 4096, 32768, t, sm);
  else if (bid == 1) scan_block(p.cnt2, p.rs2, 2048, 16384, t, sm);
  __threadfence();
  grid.sync();

  // ---------- P2: scatter to CSR ----------
  for (int lt = bid; lt < 192; lt += G) {
    if (lt < 128) {
      int e = lt * NT + t;
      int pos = atomicAdd(&p.cnt1[p.L1r[e]], 1);
      p.ccol1[pos] = p.L1c[e];
      p.cval1[pos] = p.L1v[e];
    } else {
      int e = (lt - 128) * NT + t;
      int pos = atomicAdd(&p.cnt2[p.L2r[e]], 1);
      p.ccol2[pos] = p.L2c[e];
      p.cval2[pos] = p.L2v[e];
    }
  }
  __threadfence();
  grid.sync();

  // ---------- P3: layer-1 recurrence; T_{k-1} in LDS (16 KB), T_{k-2}/T_k in regs ----------
  for (int b = bid; b < 64; b += G) {
    float* fa = sm;                     // T_{k-1}[v], 4096 floats
    float t2[16], zn[16];
    __syncthreads();
#pragma unroll
    for (int j = 0; j < 16; ++j) {
      int v = j * NT + t;
      float xv = p.x[(size_t)b * 4096 + v];
      fa[v] = xv;
      p.T1[(size_t)b * 4096 + v] = xv;          // T1[0][b][v]
    }
    __syncthreads();
    for (int k = 1; k < 25; ++k) {
#pragma unroll
      for (int j = 0; j < 16; ++j) {
        int v = j * NT + t;
        int e0 = p.rs1[v], e1 = p.rs1[v + 1];
        float s = 0.f;
        int e = e0;
        for (; e + 4 <= e1; e += 4) {
          int u0 = p.ccol1[e], u1 = p.ccol1[e + 1], u2 = p.ccol1[e + 2], u3 = p.ccol1[e + 3];
          float c0 = p.cval1[e], c1 = p.cval1[e + 1], c2 = p.cval1[e + 2], c3 = p.cval1[e + 3];
          s = fmaf(c0, fa[u0], s); s = fmaf(c1, fa[u1], s);
          s = fmaf(c2, fa[u2], s); s = fmaf(c3, fa[u3], s);
        }
        for (; e < e1; ++e) s = fmaf(p.cval1[e], fa[p.ccol1[e]], s);
        float told = fa[v];
        float t1v = s - told;                   // coef = 2/lmax = 1
        float z = (k == 1) ? t1v : 2.f * t1v - t2[j];
        t2[j] = told;
        zn[j] = z;
        p.T1[((size_t)k * 64 + b) * 4096 + v] = z;
      }
      __syncthreads();
#pragma unroll
      for (int j = 0; j < 16; ++j) fa[j * NT + t] = zn[j];
      __syncthreads();
    }
  }
  __threadfence();
  grid.sync();

  // ---------- P4: conv1 dense + relu + pool -> zA [chunk8][v2 2048][bp8*f32] ----------
  {
    for (int idx = t; idx < 800; idx += NT) sm[idx] = p.W1[idx];
    if (t < 32) sm[800 + t] = p.b1[t];
    __syncthreads();
    for (int lt = bid; lt < 1024; lt += G) {
      const int b = lt >> 4, vt = lt & 15;
      const int v = vt * NT + t;
      float acc[32];
#pragma unroll
      for (int f = 0; f < 32; ++f) acc[f] = sm[800 + f];
      for (int k = 0; k < 25; ++k) {
        float tv = p.T1[((size_t)k * 64 + b) * 4096 + v];
#pragma unroll
        for (int f = 0; f < 32; ++f) acc[f] = fmaf(tv, sm[f * 25 + k], acc[f]);
      }
#pragma unroll
      for (int f = 0; f < 32; ++f) {
        float r = fmaxf(acc[f], 0.f);
        acc[f] = fmaxf(r, __shfl_xor(r, 1, 64));
      }
      if ((t & 1) == 0) {
        const int chunk = b >> 3, bp = b & 7;
        size_t obase = ((size_t)chunk * 2048 + (v >> 1)) * 256 + bp * 32;
#pragma unroll
        for (int q = 0; q < 8; ++q) {
          float4 w = make_float4(acc[4 * q], acc[4 * q + 1], acc[4 * q + 2], acc[4 * q + 3]);
          *(float4*)&p.zA[obase + 4 * q] = w;
        }
      }
    }
  }
  __threadfence();
  grid.sync();

  // ---------- P5: layer-2 fused recurrence + register-resident y2 + relu/pool ----------
  {
    const int bp = t >> 5, g = t & 31;
    int myto[4];
    int ntile = 0;
    for (int to = bid; to < 2048; to += G) myto[ntile++] = to;   // <=4 since G>=512
    float accA[4][8], accB[4][8];
    {
      float biasA = p.b2[g], biasB = p.b2[g + 32];
#pragma unroll
      for (int j = 0; j < 4; ++j)
#pragma unroll
        for (int i = 0; i < 8; ++i) { accA[j][i] = biasA; accB[j][i] = biasB; }
    }
    float* zS = sm;            // 2048
    float* wS = sm + 2048;     // 2048, layout [fin][f] (conflict-free unpadded)

    // k = 0: dense from zA (T_0)
    for (int idx = t; idx < 2048; idx += NT) wS[idx] = p.wT2[idx];
#pragma unroll
    for (int j = 0; j < 4; ++j) {
      if (j >= ntile) break;
      const int to = myto[j];
      const size_t cbase = (size_t)(to & 7) << 19;
      const int v0 = (to >> 3) * 8;
      __syncthreads();
#pragma unroll
      for (int i = 0; i < 8; ++i) zS[i * 256 + t] = p.zA[cbase + (size_t)(v0 + i) * 256 + t];
      __syncthreads();
#pragma unroll
      for (int i = 0; i < 8; ++i) {
        float a0 = accA[j][i], a1 = accB[j][i];
#pragma unroll
        for (int fin = 0; fin < 32; ++fin) {
          float zv = zS[i * 256 + bp * 32 + fin];
          a0 = fmaf(zv, wS[fin * 64 + g], a0);
          a1 = fmaf(zv, wS[fin * 64 + 32 + g], a1);
        }
        accA[j][i] = a0; accB[j][i] = a1;
      }
    }

    const float* zPa = p.zA;
    float* zOa = p.zB;
    for (int k = 1; k < 25; ++k) {
      __syncthreads();                      // prior dense done with wS/zS
      for (int idx = t; idx < 2048; idx += NT) wS[idx] = p.wT2[k * 2048 + idx];
#pragma unroll
      for (int j = 0; j < 4; ++j) {
        if (j >= ntile) break;
        const int to = myto[j];
        const size_t cbase = (size_t)(to & 7) << 19;
        const int v0 = (to >> 3) * 8;
        float ztmp[8];
#pragma unroll
        for (int i = 0; i < 8; ++i) {
          int v = v0 + i;
          size_t rb = cbase + (size_t)v * 256;
          int e0 = p.rs2[v], e1 = p.rs2[v + 1];
          float s = 0.f;
          int e = e0;
          for (; e + 4 <= e1; e += 4) {
            int u0 = p.ccol2[e], u1 = p.ccol2[e + 1], u2 = p.ccol2[e + 2], u3 = p.ccol2[e + 3];
            float c0 = p.cval2[e], c1 = p.cval2[e + 1], c2 = p.cval2[e + 2], c3 = p.cval2[e + 3];
            s = fmaf(c0, zPa[cbase + (size_t)u0 * 256 + t], s);
            s = fmaf(c1, zPa[cbase + (size_t)u1 * 256 + t], s);
            s = fmaf(c2, zPa[cbase + (size_t)u2 * 256 + t], s);
            s = fmaf(c3, zPa[cbase + (size_t)u3 * 256 + t], s);
          }
          for (; e < e1; ++e) s = fmaf(p.cval2[e], zPa[cbase + (size_t)p.ccol2[e] * 256 + t], s);
          float t1v = s - zPa[rb + t];
          float z = (k == 1) ? t1v : 2.f * t1v - zOa[rb + t];  // own-elem read-then-write
          zOa[rb + t] = z;
          ztmp[i] = z;
        }
        __syncthreads();                    // previous tile's dense done reading zS
#pragma unroll
        for (int i = 0; i < 8; ++i) zS[i * 256 + t] = ztmp[i];
        __syncthreads();
#pragma unroll
        for (int i = 0; i < 8; ++i) {
          float a0 = accA[j][i], a1 = accB[j][i];
#pragma unroll
          for (int fin = 0; fin < 32; ++fin) {
            float zv = zS[i * 256 + bp * 32 + fin];
            a0 = fmaf(zv, wS[fin * 64 + g], a0);
            a1 = fmaf(zv, wS[fin * 64 + 32 + g], a1);
          }
          accA[j][i] = a0; accB[j][i] = a1;
        }
      }
      __threadfence();
      grid.sync();                          // T_k visible before step k+1 gathers
      const float* tmp = zPa; zPa = zOa; zOa = (float*)tmp;
    }

    // epilogue: relu + pool(2) -> h2T[(u*64+f)*64 + b]
#pragma unroll
    for (int j = 0; j < 4; ++j) {
      if (j >= ntile) break;
      const int to = myto[j];
      const int chunk = to & 7, vg = to >> 3;
      const int b = chunk * 8 + bp;
#pragma unroll
      for (int q = 0; q < 4; ++q) {
        float m0 = fmaxf(fmaxf(accA[j][2 * q], 0.f), fmaxf(accA[j][2 * q + 1], 0.f));
        float m1 = fmaxf(fmaxf(accB[j][2 * q], 0.f), fmaxf(accB[j][2 * q + 1], 0.f));
        size_t u = (size_t)(vg * 4 + q);
        p.h2T[(u * 64 + g) * 64 + b] = m0;
        p.h2T[(u * 64 + 32 + g) * 64 + b] = m1;
      }
    }
  }
  __threadfence();
  grid.sync();

  // ---------- P6: fc1 split-K GEMM; hT in LDS, weight rows via L1 ----------
  {
    float* hT = sm;                            // 32 k x 64 b = 2048
    const int tb = t & 15, tj = t >> 4;
    for (int lt = bid; lt < 1024; lt += G) {   // 8 j-tiles x 128 k-splits
      const int jt = lt & 7, ks = lt >> 3;
      const int j0g = jt * 64;
      float acc[4][4];
#pragma unroll
      for (int i = 0; i < 4; ++i)
#pragma unroll
        for (int j = 0; j < 4; ++j) acc[i][j] = 0.f;
      for (int kc = 0; kc < 16; ++kc) {
        int kbase = ks * 512 + kc * 32;
        __syncthreads();
        for (int idx = t; idx < 2048; idx += NT)
          hT[idx] = p.h2T[(size_t)kbase * 64 + idx];
        __syncthreads();
        for (int kl = 0; kl < 32; ++kl) {
          float hv[4], wv[4];
#pragma unroll
          for (int bb = 0; bb < 4; ++bb) hv[bb] = hT[kl * 64 + tb * 4 + bb];
#pragma unroll
          for (int jj = 0; jj < 4; ++jj)
            wv[jj] = p.fW1[(size_t)(j0g + tj * 4 + jj) * 65536 + kbase + kl];
#pragma unroll
          for (int bb = 0; bb < 4; ++bb)
#pragma unroll
            for (int jj = 0; jj < 4; ++jj) acc[bb][jj] = fmaf(hv[bb], wv[jj], acc[bb][jj]);
        }
      }
#pragma unroll
      for (int bb = 0; bb < 4; ++bb)
#pragma unroll
        for (int jj = 0; jj < 4; ++jj)
          atomicAdd(&p.fc1o[(j0g + tj * 4 + jj) * 64 + tb * 4 + bb], acc[bb][jj]);
    }
  }
  __threadfence();
  grid.sync();

  // ---------- P7: fc2 ----------
  if (bid < 10 && t < 64) {
    const int c = bid, b = t;
    float s = p.fb2[c];
    for (int j = 0; j < 512; ++j) {
      float a = fmaxf(p.fc1o[j * 64 + b] + p.fb1[j], 0.f);
      s = fmaf(a, p.fW2[c * 512 + j], s);
    }
    p.out[b * 10 + c] = s;
  }
}

extern "C" void kernel_launch(void* const* d_in, const int* in_sizes, int n_in,
                              void* d_out, int out_size, void* d_ws, size_t ws_size,
                              hipStream_t stream) {
  Pars prm;
  prm.x   = (const float*)d_in[0];
  prm.L1r = (const int*)d_in[1];
  prm.L1c = (const int*)d_in[2];
  prm.L1v = (const float*)d_in[3];
  prm.L2r = (const int*)d_in[4];
  prm.L2c = (const int*)d_in[5];
  prm.L2v = (const float*)d_in[6];
  prm.W1  = (const float*)d_in[7];
  prm.b1  = (const float*)d_in[8];
  prm.W2  = (const float*)d_in[9];
  prm.b2  = (const float*)d_in[10];
  prm.fW1 = (const float*)d_in[11];
  prm.fb1 = (const float*)d_in[12];
  prm.fW2 = (const float*)d_in[13];
  prm.fb2 = (const float*)d_in[14];
  prm.out = (float*)d_out;

  float* Wf = (float*)d_ws;
  size_t off = 0;
  auto alloc = [&](size_t n) { float* q = Wf + off; off += n; return q; };
  prm.cnt1  = (int*)alloc(4096);
  prm.rs1   = (int*)alloc(4100);
  prm.ccol1 = (int*)alloc(32768);
  prm.cnt2  = (int*)alloc(2048);
  prm.rs2   = (int*)alloc(2052);
  prm.ccol2 = (int*)alloc(16384);
  prm.cval1 = alloc(32768);
  prm.cval2 = alloc(16384);
  prm.wT2   = alloc(51200);            // [k][fin][f]
  prm.fc1o  = alloc(32768);
  prm.T1    = alloc(6553600);          // 25 x [64 b][4096 v]; h2T overlays (dead after P4)
  prm.zA    = alloc(4194304);          // layer-2 state ping [chunk8][2048 v][8 b'][32 f]
  prm.zB    = alloc(4194304);          // layer-2 state pong
  prm.h2T   = prm.T1;                  // [65536 i][64 b] overlays T1

  hipMemsetAsync(prm.cnt1, 0, 4096 * sizeof(int), stream);
  hipMemsetAsync(prm.cnt2, 0, 2048 * sizeof(int), stream);

  // Size the cooperative grid to what the runtime will actually accept.
  int occ = 0;
  hipOccupancyMaxActiveBlocksPerMultiprocessor(&occ, (const void*)k_all, NT, 0);
  int dev = 0;
  hipGetDevice(&dev);
  int cus = 0;
  hipDeviceGetAttribute(&cus, hipDeviceAttributeMultiprocessorCount, dev);
  long long gl = (long long)occ * (long long)cus;
  int G = (int)(gl < 512 ? 512 : (gl > 1024 ? 1024 : gl));

  void* args[] = { (void*)&prm };
  hipLaunchCooperativeKernel((const void*)k_all, dim3(G), dim3(NT), args, 0, stream);
}

// Round 6
// 1694.121 us; speedup vs baseline: 8.5233x; 8.5233x over previous
//
#include <hip/hip_runtime.h>
#include <hip/hip_bf16.h>

#define V1 4096
#define V2 2048
#define NNZ1 32768
#define NNZ2 16384

typedef unsigned short u16;
typedef unsigned int u32;

static __device__ __forceinline__ float bf2f(u16 u) {
  union { u32 i; float f; } c; c.i = ((u32)u) << 16; return c.f;
}
static __device__ __forceinline__ u16 f2bf(float f) {
  union { u32 i; float f; } c; c.f = f;
  u32 r = c.i + 0x7FFFu + ((c.i >> 16) & 1u);   // round-nearest-even
  return (u16)(r >> 16);
}

// ---------------- CSR build + weight transpose ----------------
__global__ void k_hist(const int* __restrict__ L1r, const int* __restrict__ L2r,
                       const float* __restrict__ W2, float* __restrict__ wT2,
                       int* __restrict__ cnt1, int* __restrict__ cnt2) {
  int lt = blockIdx.x, t = threadIdx.x;
  if (lt < 128) {
    atomicAdd(&cnt1[L1r[lt * 256 + t]], 1);
  } else if (lt < 192) {
    atomicAdd(&cnt2[L2r[(lt - 128) * 256 + t]], 1);
  } else {                                   // wT2[k][fin][f] = W2[f][fin*25+k]
    int idx = (lt - 192) * 256 + t;          // 51200
    int k = idx >> 11, r = idx & 2047;
    int fin = r >> 6, f = r & 63;
    wT2[idx] = W2[f * 800 + fin * 25 + k];
  }
}

__global__ void k_scan(int* __restrict__ cnt1, int* __restrict__ rs1,
                       int* __restrict__ cnt2, int* __restrict__ rs2) {
  __shared__ int sums[256];
  int t = threadIdx.x;
  int* cnt = blockIdx.x == 0 ? cnt1 : cnt2;
  int* rs  = blockIdx.x == 0 ? rs1 : rs2;
  int V    = blockIdx.x == 0 ? V1 : V2;
  int nnz  = blockIdx.x == 0 ? NNZ1 : NNZ2;
  int chunk = V / 256, base = t * chunk, s = 0;
  for (int i = 0; i < chunk; ++i) s += cnt[base + i];
  sums[t] = s;
  __syncthreads();
  if (t == 0) {
    int run = 0;
    for (int i = 0; i < 256; ++i) { int c = sums[i]; sums[i] = run; run += c; }
  }
  __syncthreads();
  int pfx = sums[t];
  for (int i = 0; i < chunk; ++i) {
    int c = cnt[base + i];
    rs[base + i] = pfx;
    cnt[base + i] = pfx;                     // cursor for scatter
    pfx += c;
  }
  if (t == 0) rs[V] = nnz;
}

__global__ void k_scatter(const int* __restrict__ L1r, const int* __restrict__ L1c,
                          const float* __restrict__ L1v,
                          const int* __restrict__ L2r, const int* __restrict__ L2c,
                          const float* __restrict__ L2v,
                          int* __restrict__ cur1, int* __restrict__ ccol1, float* __restrict__ cval1,
                          int* __restrict__ cur2, int* __restrict__ ccol2, float* __restrict__ cval2) {
  int lt = blockIdx.x, t = threadIdx.x;
  if (lt < 128) {
    int e = lt * 256 + t;
    int pos = atomicAdd(&cur1[L1r[e]], 1);
    ccol1[pos] = L1c[e];
    cval1[pos] = L1v[e];
  } else {
    int e = (lt - 128) * 256 + t;
    int pos = atomicAdd(&cur2[L2r[e]], 1);
    ccol2[pos] = L2c[e];
    cval2[pos] = L2v[e];
  }
}

// ---------------- layer-1 recurrence: block = one batch col, LDS-resident ----------------
__global__ void __launch_bounds__(512) k_l1rec(
    const float* __restrict__ x, const int* __restrict__ rs1,
    const int* __restrict__ ccol1, const float* __restrict__ cval1,
    u16* __restrict__ T1) {
  __shared__ float fa[V1];
  const int b = blockIdx.x, t = threadIdx.x;
  float t2r[8], zr[8];
#pragma unroll
  for (int j = 0; j < 8; ++j) {
    int v = t + j * 512;
    float xv = x[(size_t)b * V1 + v];
    fa[v] = xv;
    T1[((size_t)v * 64 + b) * 32 + 0] = f2bf(xv);
  }
  __syncthreads();
  for (int k = 1; k < 25; ++k) {
#pragma unroll
    for (int j = 0; j < 8; ++j) {
      int v = t + j * 512;
      int e0 = rs1[v], e1 = rs1[v + 1];
      float s = 0.f;
      int e = e0;
      for (; e + 4 <= e1; e += 4) {
        int u0 = ccol1[e], u1 = ccol1[e + 1], u2 = ccol1[e + 2], u3 = ccol1[e + 3];
        float c0 = cval1[e], c1 = cval1[e + 1], c2 = cval1[e + 2], c3 = cval1[e + 3];
        s = fmaf(c0, fa[u0], s); s = fmaf(c1, fa[u1], s);
        s = fmaf(c2, fa[u2], s); s = fmaf(c3, fa[u3], s);
      }
      for (; e < e1; ++e) s = fmaf(cval1[e], fa[ccol1[e]], s);
      float old = fa[v];
      float t1v = s - old;                    // coef = 2/lmax = 1
      zr[j] = (k == 1) ? t1v : 2.f * t1v - t2r[j];
    }
    __syncthreads();
#pragma unroll
    for (int j = 0; j < 8; ++j) {
      int v = t + j * 512;
      t2r[j] = fa[v];
      fa[v] = zr[j];
      T1[((size_t)v * 64 + b) * 32 + k] = f2bf(zr[j]);
    }
    __syncthreads();
  }
}

// ---------------- conv1 dense + relu + pool -> z0 [b][v2][32] ----------------
__global__ void k_conv1(const u16* __restrict__ T1, const float* __restrict__ W1,
                        const float* __restrict__ b1, float* __restrict__ z0) {
  __shared__ float w1s[800];
  __shared__ float b1s[32];
  const int b = blockIdx.x & 63, uc = blockIdx.x >> 6, t = threadIdx.x;
  for (int idx = t; idx < 800; idx += 256) w1s[idx] = W1[idx];
  if (t < 32) b1s[t] = b1[t];
  __syncthreads();
  const int u = uc * 256 + t;
  const u16* r1 = T1 + ((size_t)(2 * u) * 64 + b) * 32;
  const u16* r2 = T1 + ((size_t)(2 * u + 1) * 64 + b) * 32;
  float a1[25], a2[25];
  {
    uint4 q[4], p[4];
#pragma unroll
    for (int i = 0; i < 4; ++i) { q[i] = ((const uint4*)r1)[i]; p[i] = ((const uint4*)r2)[i]; }
    const u16* qa = (const u16*)q;
    const u16* pa = (const u16*)p;
#pragma unroll
    for (int k = 0; k < 25; ++k) { a1[k] = bf2f(qa[k]); a2[k] = bf2f(pa[k]); }
  }
  float mout[32];
#pragma unroll
  for (int f = 0; f < 32; ++f) {
    float s1 = b1s[f], s2 = b1s[f];
#pragma unroll
    for (int k = 0; k < 25; ++k) {
      float w = w1s[f * 25 + k];
      s1 = fmaf(a1[k], w, s1);
      s2 = fmaf(a2[k], w, s2);
    }
    mout[f] = fmaxf(fmaxf(s1, 0.f), fmaxf(s2, 0.f));
  }
  float4* dst = (float4*)&z0[((size_t)b * V2 + u) * 32];
#pragma unroll
  for (int q = 0; q < 8; ++q)
    dst[q] = make_float4(mout[4 * q], mout[4 * q + 1], mout[4 * q + 2], mout[4 * q + 3]);
}

// ---------------- layer-2 recurrence: block = (b, 8-fin group), all v in LDS ----------------
// Fin = 32 -> exactly 4 feature groups of 8. Grid MUST be bs*4 (fg in [0,4)).
// Writes all 25 Chebyshev slices to T2 (bf16) laid out [m = v*bs+bl][kappa = k*32+fin].
__global__ void __launch_bounds__(512) k_l2rec(
    const float* __restrict__ z0, const int* __restrict__ rs2,
    const int* __restrict__ ccol2, const float* __restrict__ cval2,
    u16* __restrict__ T2, int b0, int bs) {
  __shared__ float TkS[V2 * 8];               // 64 KB: [v][8 fin]
  const int bl = blockIdx.x % bs, fg = blockIdx.x / bs;   // fg in [0,4)
  const int b = b0 + bl, f0 = fg * 8;
  const int t = threadIdx.x;
  const int f = t & 7, vl = t >> 3;           // vl in [0,64)
  for (int idx = t; idx < V2 * 8; idx += 512) {
    int v = idx >> 3, ff = idx & 7;
    TkS[idx] = z0[((size_t)b * V2 + v) * 32 + f0 + ff];
  }
  __syncthreads();
  // slice 0
#pragma unroll
  for (int j = 0; j < 4; ++j) {
    int v = t + j * 512;
    const float* s = &TkS[v * 8];
    uint4 w;
    w.x = (u32)f2bf(s[0]) | ((u32)f2bf(s[1]) << 16);
    w.y = (u32)f2bf(s[2]) | ((u32)f2bf(s[3]) << 16);
    w.z = (u32)f2bf(s[4]) | ((u32)f2bf(s[5]) << 16);
    w.w = (u32)f2bf(s[6]) | ((u32)f2bf(s[7]) << 16);
    *(uint4*)(T2 + (size_t)(v * bs + bl) * 800 + f0) = w;
  }
  float t2r[32], zr[32];
  for (int k = 1; k < 25; ++k) {
#pragma unroll
    for (int i = 0; i < 32; ++i) {
      int v = vl + (i << 6);
      int e0 = rs2[v], e1 = rs2[v + 1];
      float s = 0.f;
      int e = e0;
      for (; e + 4 <= e1; e += 4) {
        int u0 = ccol2[e], u1 = ccol2[e + 1], u2 = ccol2[e + 2], u3 = ccol2[e + 3];
        float c0 = cval2[e], c1 = cval2[e + 1], c2 = cval2[e + 2], c3 = cval2[e + 3];
        s = fmaf(c0, TkS[u0 * 8 + f], s); s = fmaf(c1, TkS[u1 * 8 + f], s);
        s = fmaf(c2, TkS[u2 * 8 + f], s); s = fmaf(c3, TkS[u3 * 8 + f], s);
      }
      for (; e < e1; ++e) s = fmaf(cval2[e], TkS[ccol2[e] * 8 + f], s);
      float old = TkS[v * 8 + f];
      float t1v = s - old;
      zr[i] = (k == 1) ? t1v : 2.f * t1v - t2r[i];
    }
    __syncthreads();
#pragma unroll
    for (int i = 0; i < 32; ++i) {
      int a = (vl + (i << 6)) * 8 + f;
      t2r[i] = TkS[a];
      TkS[a] = zr[i];
    }
    __syncthreads();
#pragma unroll
    for (int j = 0; j < 4; ++j) {
      int v = t + j * 512;
      const float* s = &TkS[v * 8];
      uint4 w;
      w.x = (u32)f2bf(s[0]) | ((u32)f2bf(s[1]) << 16);
      w.y = (u32)f2bf(s[2]) | ((u32)f2bf(s[3]) << 16);
      w.z = (u32)f2bf(s[4]) | ((u32)f2bf(s[5]) << 16);
      w.w = (u32)f2bf(s[6]) | ((u32)f2bf(s[7]) << 16);
      *(uint4*)(T2 + (size_t)(v * bs + bl) * 800 + (size_t)k * 32 + f0) = w;
    }
    // safe: next step's gathers and this pack both only read TkS; next write is
    // behind the __syncthreads() that follows the gathers.
  }
}

// ---------------- conv2 dense GEMM over the bf16 basis + relu + pool -> h2T ----------------
__global__ void k_conv2g(const u16* __restrict__ T2, const float* __restrict__ wT2,
                         const float* __restrict__ b2, float* __restrict__ h2T,
                         int b0, int bs, int lbs) {
  __shared__ float wS[32 * 64];               // [kl][f]
  __shared__ float yS[128 * 65];              // padded rows
  const int t = threadIdx.x;
  const int r = t & 127, fh = t >> 7, fbase = fh * 32;
  const int P = 128 >> lbs;                   // v's per tile
  const int v0 = blockIdx.x * P;
  const size_t row = (size_t)blockIdx.x * 128 + r;
  const u16* arow = T2 + row * 800;
  float acc[32];
#pragma unroll
  for (int q = 0; q < 32; ++q) acc[q] = b2[fbase + q];
  for (int kc = 0; kc < 25; ++kc) {
    __syncthreads();
    for (int idx = t; idx < 2048; idx += 256) wS[idx] = wT2[kc * 2048 + idx];
    __syncthreads();
    float a[32];
    {
      const uint4* ap = (const uint4*)(arow + kc * 32);
      uint4 q0 = ap[0], q1 = ap[1], q2 = ap[2], q3 = ap[3];
      const u16* av = (const u16*)&q0;
#pragma unroll
      for (int i = 0; i < 8; ++i) a[i] = bf2f(av[i]);
      av = (const u16*)&q1;
#pragma unroll
      for (int i = 0; i < 8; ++i) a[8 + i] = bf2f(av[i]);
      av = (const u16*)&q2;
#pragma unroll
      for (int i = 0; i < 8; ++i) a[16 + i] = bf2f(av[i]);
      av = (const u16*)&q3;
#pragma unroll
      for (int i = 0; i < 8; ++i) a[24 + i] = bf2f(av[i]);
    }
#pragma unroll
    for (int kl = 0; kl < 32; ++kl) {
      float avv = a[kl];
      const float* wrow = &wS[kl * 64 + fbase];
#pragma unroll
      for (int q = 0; q < 32; ++q) acc[q] = fmaf(avv, wrow[q], acc[q]);
    }
  }
#pragma unroll
  for (int q = 0; q < 32; ++q) yS[r * 65 + fbase + q] = acc[q];
  __syncthreads();
  const int u0 = v0 >> 1;
#pragma unroll
  for (int j = 0; j < 16; ++j) {
    int idx = t + j * 256;                    // 4096 pooled outputs
    int bl = idx & (bs - 1);
    int rest = idx >> lbs;
    int ff = rest & 63;
    int ul = rest >> 6;
    int r1 = ((2 * ul) << lbs) + bl;
    int r2 = r1 + bs;
    float m = fmaxf(fmaxf(yS[r1 * 65 + ff], 0.f), fmaxf(yS[r2 * 65 + ff], 0.f));
    h2T[(size_t)((u0 + ul) * 64 + ff) * 64 + b0 + bl] = m;
  }
}

// ---------------- fc1: split-K GEMM, float4 weight streaming, atomic reduce ----------------
__global__ void k_fc1(const float* __restrict__ h2T, const float* __restrict__ fW1,
                      float* __restrict__ fc1o) {
  __shared__ float wS[16 * 256];
  const int jt = blockIdx.x & 31, ks = blockIdx.x >> 5;   // 32 j-tiles(16) x 32 k-splits(2048)
  const int j0 = jt * 16, k0 = ks * 2048;
  const int t = threadIdx.x;
  const int b = t & 63, jl = t >> 6;                      // 4 j-lanes
  float acc[4] = {0.f, 0.f, 0.f, 0.f};
  for (int kc = 0; kc < 8; ++kc) {
    int kbase = k0 + kc * 256;
    __syncthreads();
    for (int fi = t; fi < 1024; fi += 256) {
      int rowj = fi >> 6, colq = fi & 63;
      *(float4*)&wS[rowj * 256 + colq * 4] =
          *(const float4*)&fW1[(size_t)(j0 + rowj) * 65536 + kbase + colq * 4];
    }
    __syncthreads();
    for (int kl = 0; kl < 256; ++kl) {
      float hv = h2T[(size_t)(kbase + kl) * 64 + b];
#pragma unroll
      for (int q = 0; q < 4; ++q) acc[q] = fmaf(hv, wS[(jl * 4 + q) * 256 + kl], acc[q]);
    }
  }
#pragma unroll
  for (int q = 0; q < 4; ++q) atomicAdd(&fc1o[(j0 + jl * 4 + q) * 64 + b], acc[q]);
}

__global__ void k_fc2(const float* __restrict__ fc1o, const float* __restrict__ fb1,
                      const float* __restrict__ fW2, const float* __restrict__ fb2,
                      float* __restrict__ out) {
  const int c = blockIdx.x, b = threadIdx.x;
  float s = fb2[c];
  for (int j = 0; j < 512; ++j) {
    float a = fmaxf(fc1o[j * 64 + b] + fb1[j], 0.f);
    s = fmaf(a, fW2[c * 512 + j], s);
  }
  out[b * 10 + c] = s;
}

extern "C" void kernel_launch(void* const* d_in, const int* in_sizes, int n_in,
                              void* d_out, int out_size, void* d_ws, size_t ws_size,
                              hipStream_t stream) {
  const float* x    = (const float*)d_in[0];
  const int* L1r    = (const int*)d_in[1];
  const int* L1c    = (const int*)d_in[2];
  const float* L1v  = (const float*)d_in[3];
  const int* L2r    = (const int*)d_in[4];
  const int* L2c    = (const int*)d_in[5];
  const float* L2v  = (const float*)d_in[6];
  const float* W1   = (const float*)d_in[7];
  const float* b1   = (const float*)d_in[8];
  const float* W2   = (const float*)d_in[9];
  const float* b2   = (const float*)d_in[10];
  const float* fW1  = (const float*)d_in[11];
  const float* fb1  = (const float*)d_in[12];
  const float* fW2  = (const float*)d_in[13];
  const float* fb2  = (const float*)d_in[14];
  float* out = (float*)d_out;

  float* Wf = (float*)d_ws;
  size_t off = 0;
  auto alloc = [&](size_t n) { float* q = Wf + off; off += n; return q; };
  int* cnt1   = (int*)alloc(4096);
  int* rs1    = (int*)alloc(4100);
  int* ccol1  = (int*)alloc(NNZ1);
  int* cnt2   = (int*)alloc(2048);
  int* rs2    = (int*)alloc(2052);
  int* ccol2  = (int*)alloc(NNZ2);
  float* cval1 = alloc(NNZ1);
  float* cval2 = alloc(NNZ2);
  float* wT2   = alloc(51200);
  float* fc1o  = alloc(32768);
  float* z0    = alloc(4194304);        // [64 b][2048 v][32 f] fp32, 16.8 MB
  float* h2T   = alloc(4194304);        // [65536 i][64 b] fp32, 16.8 MB
  size_t fixedB = off * 4;

  // Batch split so the bf16 Chebyshev basis T2 fits the workspace.
  int ns = 8;
  for (int c = 1; c <= 8; c <<= 1) {
    size_t t2b = (size_t)V2 * (64 / c) * 800 * 2;
    size_t big = t2b > 16777216ull ? t2b : 16777216ull;   // T1 (16.8 MB) overlays same region
    if (fixedB + big + 65536 <= ws_size) { ns = c; break; }
  }
  const int bs = 64 / ns;
  const int lbs = (bs == 64) ? 6 : (bs == 32) ? 5 : (bs == 16) ? 4 : 3;
  u16* T1 = (u16*)(Wf + off);           // [m1 = v*64+b][32 (25 used)] bf16
  u16* T2 = (u16*)(Wf + off);           // [ms = v*bs+bl][800] bf16 — overlays T1 (dead)

  hipMemsetAsync(cnt1, 0, 4096 * sizeof(int), stream);
  hipMemsetAsync(cnt2, 0, 2048 * sizeof(int), stream);
  hipMemsetAsync(fc1o, 0, 32768 * sizeof(float), stream);

  k_hist<<<392, 256, 0, stream>>>(L1r, L2r, W2, wT2, cnt1, cnt2);
  k_scan<<<2, 256, 0, stream>>>(cnt1, rs1, cnt2, rs2);
  k_scatter<<<192, 256, 0, stream>>>(L1r, L1c, L1v, L2r, L2c, L2v,
                                     cnt1, ccol1, cval1, cnt2, ccol2, cval2);

  k_l1rec<<<64, 512, 0, stream>>>(x, rs1, ccol1, cval1, T1);
  k_conv1<<<512, 256, 0, stream>>>(T1, W1, b1, z0);

  for (int s = 0; s < ns; ++s) {
    int b0 = s * bs;
    k_l2rec<<<bs * 4, 512, 0, stream>>>(z0, rs2, ccol2, cval2, T2, b0, bs);   // Fin=32 -> 4 fgroups
    k_conv2g<<<16 * bs, 256, 0, stream>>>(T2, wT2, b2, h2T, b0, bs, lbs);
  }

  k_fc1<<<1024, 256, 0, stream>>>(h2T, fW1, fc1o);
  k_fc2<<<10, 64, 0, stream>>>(fc1o, fb1, fW2, fb2, out);
}